// Round 5
// baseline (81.594 us; speedup 1.0000x reference)
//
#include <hip/hip_runtime.h>
#include <hip/hip_bf16.h>

#define EPS 1e-5f
#define NPTS 262144
#define NB 16
#define ACBLK 1024

typedef __attribute__((ext_vector_type(8))) short bf16x8;
typedef __attribute__((ext_vector_type(4))) float f32x4;

// ws float/u32 offsets
#define WS_E    0        // 192 f
#define WS_T    192      // 1024 f
#define WS_W3   1216     // 2048 u32
#define WS_MAXG 3264     // 2048 u32 fallback merged maxima (memset 0 in mode 0)
#define WS_PMOM 5312     // 16*73 f kM partial moments
#define WS_SCRM 6480     // 1024*73 f per-block moments(9)+hist(64)
#define WS_PART 81232    // 16*2048 u32 kM partial maxima
#define WS_SMAX 114000   // 1024*2048 u32 per-block maxima

__device__ inline float decodeu(unsigned u){
  unsigned bits = (u & 0x80000000u) ? (u ^ 0x80000000u) : ~u;
  return __uint_as_float(bits);
}
__device__ inline unsigned f2bf(float f){
  unsigned u = __float_as_uint(f);
  return (u + 0x7FFFu + ((u>>16)&1u)) >> 16;
}
__device__ inline unsigned pack2bf(float lo, float hi){
  return (f2bf(hi)<<16) | (f2bf(lo) & 0xFFFFu);
}

// ---- kAC: fused moments + per-batch directional max of feats@W1'^T ----
// 1024 blocks x 256 thr; block owns 256 points (1 per thread, LDS-staged).
// 4 waves = 2 point-halves x 2 channel-halves; inner loop: broadcast
// ds_read_b128 point -> 64 channels/lane-wave -> LDS atomicMax.
__global__ __launch_bounds__(256) void kAC(const float* __restrict__ feats,
                                           const int* __restrict__ bidx,
                                           const float* __restrict__ W1,
                                           const float* __restrict__ g1,
                                           float* __restrict__ wsf, int mode) {
  __shared__ unsigned lmax[NB*128];          // 8KB
  __shared__ __align__(16) float4 sfeat[256];// 4KB
  __shared__ float hist[NB*4];
  __shared__ float red[4*9];
  int tid = threadIdx.x;
  for (int i=tid;i<NB*128;i+=256) lmax[i]=0u;
  if (tid < NB*4) hist[tid]=0.f;
  __syncthreads();
  // staging phase: 1 point per thread
  int p = blockIdx.x*256 + tid;
  float f0=feats[3*p], f1=feats[3*p+1], f2=feats[3*p+2];
  int b = bidx[p];
  sfeat[tid] = make_float4(f0,f1,f2,__int_as_float(b));
  atomicAdd(&hist[b*4+0],f0);
  atomicAdd(&hist[b*4+1],f1);
  atomicAdd(&hist[b*4+2],f2);
  atomicAdd(&hist[b*4+3],1.0f);
  int lane = tid&63, wv = tid>>6;
  { float acc[9]={f0,f1,f2,f0*f0,f0*f1,f0*f2,f1*f1,f1*f2,f2*f2};
    #pragma unroll
    for (int k=0;k<9;k++){
      float v=acc[k];
      v+=__shfl_down(v,32); v+=__shfl_down(v,16); v+=__shfl_down(v,8);
      v+=__shfl_down(v,4);  v+=__shfl_down(v,2);  v+=__shfl_down(v,1);
      if (lane==0) red[wv*9+k]=v;
    }
  }
  __syncthreads();
  // max phase
  int c = (wv&1)*64 + lane;
  float sgn = (g1[c]>=0.f)?1.f:-1.f;   // fold sign(gamma1) into direction
  float w0=W1[3*c]*sgn, w1=W1[3*c+1]*sgn, w2=W1[3*c+2]*sgn;
  const float4* sp = &sfeat[(wv>>1)*128];
  #pragma unroll 8
  for (int k=0;k<128;k++){
    float4 f = sp[k];                       // broadcast ds_read_b128
    float v = fmaf(f.z,w2,fmaf(f.y,w1,f.x*w0));
    unsigned bits = __float_as_uint(v);
    unsigned u = bits ^ (unsigned)(((int)bits>>31) | (int)0x80000000);
    int bb = __float_as_int(f.w);
    atomicMax(&lmax[bb*128+c], u);
  }
  __syncthreads();
  float* scrM = wsf + WS_SCRM + blockIdx.x*73;
  if (tid<9) scrM[tid]=red[tid]+red[9+tid]+red[18+tid]+red[27+tid];
  if (tid>=64 && tid<128) scrM[9+tid-64]=hist[tid-64];
  if (mode){
    unsigned* spo = (unsigned*)wsf + WS_SMAX + (size_t)blockIdx.x*2048;
    for (int i=tid;i<2048;i+=256) spo[i]=lmax[i];
  } else {
    unsigned* mg = (unsigned*)wsf + WS_MAXG;
    for (int i=tid;i<2048;i+=256){ unsigned v=lmax[i]; if(v) atomicMax(&mg[i],v); }
  }
}

// ---- kM: tree-merge per-block maxima 1024->16, moments 1024->16 ----
__global__ __launch_bounds__(256) void kM(float* __restrict__ wsf){
  int g = blockIdx.x >> 3, ec = blockIdx.x & 7;
  int e = ec*256 + threadIdx.x;
  const unsigned* smax = (const unsigned*)wsf + WS_SMAX;
  unsigned m = 0;
  #pragma unroll 4
  for (int k=g*64;k<g*64+64;k++){ unsigned t=smax[(size_t)k*2048+e]; m = t>m?t:m; }
  ((unsigned*)wsf)[WS_PART + g*2048 + e] = m;
  if (ec==0 && threadIdx.x<73){
    float s=0; const float* sm0 = wsf + WS_SCRM;
    #pragma unroll 4
    for (int k=g*64;k<g*64+64;k++) s += sm0[k*73+threadIdx.x];
    wsf[WS_PMOM + g*73 + threadIdx.x] = s;
  }
}

// ---- kB: all tiny math (single block, LDS-staged) ----
__global__ __launch_bounds__(256) void kB(float* __restrict__ wsf,
    const float* __restrict__ W1, const float* __restrict__ g1, const float* __restrict__ b1,
    const float* __restrict__ W2, const float* __restrict__ g2, const float* __restrict__ b2,
    const float* __restrict__ W3, int mode) {
  __shared__ float w2t[256*66];     // W2 transposed [j][c], pad 66
  __shared__ float s_w1[384];
  __shared__ float s_sc[128], s_sh[128], s_smbn[NB*128], sE[3*64], sg[64], sT[NB*64];
  __shared__ float smom[80], s_s2[64], s_t2[64];
  int tid = threadIdx.x;
  for (int i=tid;i<16384;i+=256){ int c=i>>8, j=i&255; w2t[j*66+c]=W2[i]; }
  for (int i=tid;i<384;i+=256) s_w1[i]=W1[i];
  if (mode){
    if (tid<73){ float s=0;
      #pragma unroll
      for (int g=0;g<16;g++) s += wsf[WS_PMOM+g*73+tid];
      smom[tid]=s; }
  } else {
    if (tid<73){ float s=0; const float* sm0=wsf+WS_SCRM;
      for (int k=0;k<ACBLK;k++) s += sm0[k*73+tid];
      smom[tid]=s; }
  }
  { unsigned* w3u = (unsigned*)wsf + WS_W3;
    for (int i=tid;i<2048;i+=256){
      int k=i>>5, cp=i&31;
      w3u[i] = pack2bf(W3[k*64+2*cp], W3[k*64+2*cp+1]);
    } }
  __syncthreads();
  const float invN = 1.0f/NPTS;
  if (tid < 128){
    int c=tid; float w0=s_w1[3*c],w1=s_w1[3*c+1],w2=s_w1[3*c+2];
    float mean = (w0*smom[0]+w1*smom[1]+w2*smom[2])*invN;
    float ex2 = (w0*w0*smom[3]+w1*w1*smom[6]+w2*w2*smom[8]
               + 2.f*(w0*w1*smom[4]+w0*w2*smom[5]+w1*w2*smom[7]))*invN;
    float var = ex2 - mean*mean;
    float sc = g1[c]*rsqrtf(var+EPS);
    s_sc[c]=sc; s_sh[c]=b1[c]-mean*sc;
  }
  __syncthreads();
  { const unsigned* part=(const unsigned*)wsf+WS_PART;
    const unsigned* mg=(const unsigned*)wsf+WS_MAXG;
    for (int i=tid;i<NB*128;i+=256){
      unsigned u;
      if (mode){ u=0;
        #pragma unroll
        for (int g=0;g<16;g++){ unsigned t=part[g*2048+i]; u = t>u?t:u; }
      } else u = mg[i];
      float M = decodeu(u);               // = max over batch of sign(g1)*y1
      int ch=i&127;
      s_smbn[i] = fabsf(s_sc[ch])*M + s_sh[ch];
    } }
  __syncthreads();
  { int c = tid & 63, which = tid >> 6;
    float s=0;
    for (int j=0;j<128;j++){
      float m = (which<3) ? s_sc[j]*s_w1[3*j+which] : s_sh[j];
      s += w2t[j*66+c]*m;
    }
    if (which<3) sE[which*64+c]=s; else sg[c]=s; }
  for (int i=tid;i<NB*64;i+=256){
    int b=i>>6, c=i&63; float s=0;
    for (int j=0;j<128;j++) s += w2t[(128+j)*66+c]*s_smbn[b*128+j];
    sT[i]=s;
  }
  __syncthreads();
  if (tid < 64){
    int c=tid;
    float e0=sE[c],e1=sE[64+c],e2=sE[128+c],gc=sg[c];
    float sumY = e0*smom[0]+e1*smom[1]+e2*smom[2];
    float sumYY = e0*e0*smom[3]+e1*e1*smom[6]+e2*e2*smom[8]
               + 2.f*(e0*e1*smom[4]+e0*e2*smom[5]+e1*e2*smom[7]);
    #pragma unroll
    for (int b=0;b<NB;b++){
      float nb = smom[9+b*4+3];
      float hb = gc + sT[b*64+c];
      float eS1b = e0*smom[9+b*4]+e1*smom[9+b*4+1]+e2*smom[9+b*4+2];
      sumY += nb*hb;
      sumYY += 2.f*hb*eS1b + nb*hb*hb;
    }
    float mean2 = sumY*invN;
    float var2 = sumYY*invN - mean2*mean2;
    float s2 = g2[c]*rsqrtf(var2+EPS);
    float t2 = b2[c]-mean2*s2;
    s_s2[c]=s2; s_t2[c]=t2;
    wsf[WS_E + c] = e0*s2; wsf[WS_E+64+c]=e1*s2; wsf[WS_E+128+c]=e2*s2;
  }
  __syncthreads();
  for (int i=tid;i<NB*64;i+=256){
    int c=i&63;
    wsf[WS_T + i] = (sg[c]+sT[i])*s_s2[c] + s_t2[c];
  }
}

// ---- kF: fused y2 -> bn2/relu -> z@W3.T + b3 ----
__global__ __launch_bounds__(256) void kF(const float* __restrict__ feats,
                                          const int* __restrict__ bidx,
                                          const float* __restrict__ wsf,
                                          const float* __restrict__ b3,
                                          float* __restrict__ out) {
  __shared__ __align__(16) float Tl[NB*66];
  __shared__ __align__(16) unsigned zbuf[4*64*32];   // 4 waves x 64 rows x 128B
  int tid = threadIdx.x;
  for (int i=tid;i<NB*64;i+=256) Tl[(i>>6)*66 + (i&63)] = wsf[WS_T + i];
  int lane = tid & 63, wv = tid >> 6;
  int col = lane & 15, kgrp = lane >> 4;
  const ushort* w3b = (const ushort*)((const unsigned*)wsf + WS_W3);
  bf16x8 bfr[4][2];
  #pragma unroll
  for (int n=0;n<4;n++)
    #pragma unroll
    for (int kk=0;kk<2;kk++)
      bfr[n][kk] = *(const bf16x8*)(w3b + (n*16+col)*64 + kk*32 + kgrp*8);
  float bias[4];
  #pragma unroll
  for (int n=0;n<4;n++) bias[n] = b3[n*16+col];
  __syncthreads();
  const float* Eg = wsf + WS_E;
  int p0 = (blockIdx.x*4 + wv)*64;
  int p = p0 + lane;
  float f0 = feats[3*p], f1 = feats[3*p+1], f2 = feats[3*p+2];
  int b = bidx[p];
  const float* tb = &Tl[b*66];
  unsigned rowbase = (unsigned)(wv*64+lane)*32;
  unsigned sw = (lane&7)<<2;
  #pragma unroll
  for (int j=0;j<8;j++){
    unsigned w[4];
    #pragma unroll
    for (int q=0;q<4;q++){
      int c = j*8 + q*2;
      float2 tp = *(const float2*)(tb + c);
      float y0 = fmaf(Eg[c],  f0, fmaf(Eg[64+c],  f1, fmaf(Eg[128+c],  f2, tp.x)));
      float y1 = fmaf(Eg[c+1],f0, fmaf(Eg[64+c+1],f1, fmaf(Eg[128+c+1],f2, tp.y)));
      w[q] = pack2bf(fmaxf(y0,0.f), fmaxf(y1,0.f));
    }
    uint4 ch; ch.x=w[0]; ch.y=w[1]; ch.z=w[2]; ch.w=w[3];
    *(uint4*)&zbuf[rowbase + (((unsigned)(j*4)) ^ sw)] = ch;
  }
  __syncthreads();
  bf16x8 af[4][2];
  #pragma unroll
  for (int m=0;m<4;m++){
    int row = m*16 + col;
    unsigned rb = (unsigned)(wv*64+row)*32;
    unsigned sw2 = (unsigned)(row&7)<<2;
    #pragma unroll
    for (int kk=0;kk<2;kk++){
      unsigned off = ((unsigned)(kk*16 + kgrp*4)) ^ sw2;
      af[m][kk] = *(const bf16x8*)&zbuf[rb + off];
    }
  }
  f32x4 acc[4][4];
  #pragma unroll
  for (int m=0;m<4;m++)
    #pragma unroll
    for (int n=0;n<4;n++)
      acc[m][n] = (f32x4){0.f,0.f,0.f,0.f};
  #pragma unroll
  for (int kk=0;kk<2;kk++)
    #pragma unroll
    for (int m=0;m<4;m++)
      #pragma unroll
      for (int n=0;n<4;n++)
        acc[m][n] = __builtin_amdgcn_mfma_f32_16x16x32_bf16(af[m][kk], bfr[n][kk], acc[m][n], 0,0,0);
  #pragma unroll
  for (int m=0;m<4;m++){
    int prow = p0 + m*16 + kgrp*4;
    #pragma unroll
    for (int n=0;n<4;n++){
      int cg = n*16+col;
      #pragma unroll
      for (int r=0;r<4;r++)
        out[(size_t)(prow+r)*64 + cg] = acc[m][n][r] + bias[n];
    }
  }
}

extern "C" void kernel_launch(void* const* d_in, const int* in_sizes, int n_in,
                              void* d_out, int out_size, void* d_ws, size_t ws_size,
                              hipStream_t stream) {
  const float* feats = (const float*)d_in[0];
  const int*   bidx  = (const int*)d_in[1];
  const float* W1 = (const float*)d_in[2];
  const float* g1 = (const float*)d_in[3];
  const float* b1 = (const float*)d_in[4];
  const float* W2 = (const float*)d_in[5];
  const float* g2 = (const float*)d_in[6];
  const float* b2 = (const float*)d_in[7];
  const float* W3 = (const float*)d_in[8];
  const float* b3 = (const float*)d_in[9];
  float* wsf = (float*)d_ws;
  float* out = (float*)d_out;
  size_t need = (size_t)(WS_SMAX + (size_t)ACBLK*2048)*4;
  int mode = (ws_size >= need) ? 1 : 0;
  if (!mode) (void)hipMemsetAsync((char*)d_ws + (size_t)WS_MAXG*4, 0, 2048*4, stream);
  kAC<<<ACBLK, 256, 0, stream>>>(feats, bidx, W1, g1, wsf, mode);
  if (mode) kM<<<128, 256, 0, stream>>>(wsf);
  kB<<<1, 256, 0, stream>>>(wsf, W1,g1,b1, W2,g2,b2, W3, mode);
  kF<<<1024, 256, 0, stream>>>(feats, bidx, wsf, b3, out);
}

// Round 6
// 79.838 us; speedup vs baseline: 1.0220x; 1.0220x over previous
//
#include <hip/hip_runtime.h>
#include <hip/hip_bf16.h>

#define EPS 1e-5f
#define NPTS 262144
#define NB 16
#define ACBLK 1024

typedef __attribute__((ext_vector_type(8))) short bf16x8;
typedef __attribute__((ext_vector_type(4))) float f32x4;

// ws float/u32 offsets
#define WS_E    0        // 192 f
#define WS_T    192      // 1024 f
#define WS_W3   1216     // 2048 u32
#define WS_MAXG 3264     // 2048 u32 fallback merged maxima (memset 0 in mode 0)
#define WS_PMOM 5312     // 16*73 f kM partial moments
#define WS_SCRM 6480     // 1024*73 f per-block moments(9)+hist(64)
#define WS_PART 81232    // 16*2048 u32 kM partial maxima
#define WS_SMAX 114000   // 1024*2048 u32 per-block maxima

__device__ inline float decodeu(unsigned u){
  unsigned bits = (u & 0x80000000u) ? (u ^ 0x80000000u) : ~u;
  return __uint_as_float(bits);
}
__device__ inline unsigned f2bf(float f){
  unsigned u = __float_as_uint(f);
  return (u + 0x7FFFu + ((u>>16)&1u)) >> 16;
}
__device__ inline unsigned pack2bf(float lo, float hi){
  return (f2bf(hi)<<16) | (f2bf(lo) & 0xFFFFu);
}
__device__ inline unsigned ordu(float v){
  unsigned bits = __float_as_uint(v);
  return bits ^ (unsigned)(((int)bits>>31) | (int)0x80000000);
}

// ---- kAC: fused moments + per-batch directional max of feats@W1'^T ----
// 1024 blocks x 256 thr; block owns 256 points (1/thread, LDS-staged).
// Max phase: per-thread register m[16]; batch idx is wave-uniform (point
// broadcast) -> uniform switch, zero LDS ops in the hot loop.
__global__ __launch_bounds__(256) void kAC(const float* __restrict__ feats,
                                           const int* __restrict__ bidx,
                                           const float* __restrict__ W1,
                                           const float* __restrict__ g1,
                                           float* __restrict__ wsf, int mode) {
  __shared__ unsigned lmax[NB*128];          // 8KB
  __shared__ __align__(16) float4 sfeat[256];// 4KB
  __shared__ float hist[NB*4];
  __shared__ float red[4*9];
  int tid = threadIdx.x;
  for (int i=tid;i<NB*128;i+=256) lmax[i]=0u;
  if (tid < NB*4) hist[tid]=0.f;
  __syncthreads();
  // staging phase: 1 point per thread
  int p = blockIdx.x*256 + tid;
  float f0=feats[3*p], f1=feats[3*p+1], f2=feats[3*p+2];
  int b = bidx[p];
  sfeat[tid] = make_float4(f0,f1,f2,__int_as_float(b));
  atomicAdd(&hist[b*4+0],f0);
  atomicAdd(&hist[b*4+1],f1);
  atomicAdd(&hist[b*4+2],f2);
  atomicAdd(&hist[b*4+3],1.0f);
  int lane = tid&63, wv = tid>>6;
  { float acc[9]={f0,f1,f2,f0*f0,f0*f1,f0*f2,f1*f1,f1*f2,f2*f2};
    #pragma unroll
    for (int k=0;k<9;k++){
      float v=acc[k];
      v+=__shfl_down(v,32); v+=__shfl_down(v,16); v+=__shfl_down(v,8);
      v+=__shfl_down(v,4);  v+=__shfl_down(v,2);  v+=__shfl_down(v,1);
      if (lane==0) red[wv*9+k]=v;
    }
  }
  __syncthreads();
  // max phase: register per-batch maxima
  int c = (wv&1)*64 + lane;
  float sgn = (g1[c]>=0.f)?1.f:-1.f;   // fold sign(gamma1) into direction
  float w0=W1[3*c]*sgn, w1=W1[3*c+1]*sgn, w2=W1[3*c+2]*sgn;
  const float4* sp = &sfeat[(wv>>1)*128];
  float m[16];
  #pragma unroll
  for (int q=0;q<16;q++) m[q] = -__builtin_inff();
  #pragma unroll 8
  for (int k=0;k<128;k++){
    float4 f = sp[k];                       // broadcast ds_read_b128
    float v = fmaf(f.z,w2,fmaf(f.y,w1,f.x*w0));
    int sbb = __builtin_amdgcn_readfirstlane(__float_as_int(f.w));
    switch (sbb){
      case 0:  m[0] = fmaxf(m[0], v); break;
      case 1:  m[1] = fmaxf(m[1], v); break;
      case 2:  m[2] = fmaxf(m[2], v); break;
      case 3:  m[3] = fmaxf(m[3], v); break;
      case 4:  m[4] = fmaxf(m[4], v); break;
      case 5:  m[5] = fmaxf(m[5], v); break;
      case 6:  m[6] = fmaxf(m[6], v); break;
      case 7:  m[7] = fmaxf(m[7], v); break;
      case 8:  m[8] = fmaxf(m[8], v); break;
      case 9:  m[9] = fmaxf(m[9], v); break;
      case 10: m[10] = fmaxf(m[10], v); break;
      case 11: m[11] = fmaxf(m[11], v); break;
      case 12: m[12] = fmaxf(m[12], v); break;
      case 13: m[13] = fmaxf(m[13], v); break;
      case 14: m[14] = fmaxf(m[14], v); break;
      default: m[15] = fmaxf(m[15], v); break;
    }
  }
  // merge: 16 LDS atomics per thread (once, not per point)
  #pragma unroll
  for (int q=0;q<16;q++){
    if (m[q] > -__builtin_inff()) atomicMax(&lmax[q*128+c], ordu(m[q]));
  }
  __syncthreads();
  float* scrM = wsf + WS_SCRM + blockIdx.x*73;
  if (tid<9) scrM[tid]=red[tid]+red[9+tid]+red[18+tid]+red[27+tid];
  if (tid>=64 && tid<128) scrM[9+tid-64]=hist[tid-64];
  if (mode){
    unsigned* spo = (unsigned*)wsf + WS_SMAX + (size_t)blockIdx.x*2048;
    for (int i=tid;i<2048;i+=256) spo[i]=lmax[i];
  } else {
    unsigned* mg = (unsigned*)wsf + WS_MAXG;
    for (int i=tid;i<2048;i+=256){ unsigned v=lmax[i]; if(v) atomicMax(&mg[i],v); }
  }
}

// ---- kM: tree-merge per-block maxima 1024->16, moments 1024->16 ----
__global__ __launch_bounds__(256) void kM(float* __restrict__ wsf){
  int g = blockIdx.x >> 3, ec = blockIdx.x & 7;
  int e = ec*256 + threadIdx.x;
  const unsigned* smax = (const unsigned*)wsf + WS_SMAX;
  unsigned m = 0;
  #pragma unroll 4
  for (int k=g*64;k<g*64+64;k++){ unsigned t=smax[(size_t)k*2048+e]; m = t>m?t:m; }
  ((unsigned*)wsf)[WS_PART + g*2048 + e] = m;
  if (ec==0 && threadIdx.x<73){
    float s=0; const float* sm0 = wsf + WS_SCRM;
    #pragma unroll 4
    for (int k=g*64;k<g*64+64;k++) s += sm0[k*73+threadIdx.x];
    wsf[WS_PMOM + g*73 + threadIdx.x] = s;
  }
}

// ---- kB: all tiny math (single block, reg-staged W2) ----
__global__ __launch_bounds__(256) void kB(float* __restrict__ wsf,
    const float* __restrict__ W1, const float* __restrict__ g1, const float* __restrict__ b1,
    const float* __restrict__ W2, const float* __restrict__ g2, const float* __restrict__ b2,
    const float* __restrict__ W3, int mode) {
  __shared__ float w2t[256*66];     // W2 transposed [j][c], pad 66
  __shared__ float s_w1[384];
  __shared__ float s_sc[128], s_sh[128], s_smbn[NB*128], sE[3*64], sg[64], sT[NB*64];
  __shared__ float smom[80], s_s2[64], s_t2[64];
  int tid = threadIdx.x;
  // stage W2: 16 independent float4 loads -> regs (pipelined), then LDS scatter
  float4 rw[16];
  #pragma unroll
  for (int t=0;t<16;t++) rw[t] = ((const float4*)W2)[tid + t*256];
  float4 rw3[4];
  #pragma unroll
  for (int t=0;t<4;t++) rw3[t] = ((const float4*)W3)[tid + t*256];
  for (int i=tid;i<384;i+=256) s_w1[i]=W1[i];
  #pragma unroll
  for (int t=0;t<16;t++){
    int q = tid + t*256;
    int c = q>>6, j0 = (q&63)*4;
    w2t[(j0+0)*66+c]=rw[t].x; w2t[(j0+1)*66+c]=rw[t].y;
    w2t[(j0+2)*66+c]=rw[t].z; w2t[(j0+3)*66+c]=rw[t].w;
  }
  { unsigned* w3u = (unsigned*)wsf + WS_W3;
    #pragma unroll
    for (int t=0;t<4;t++){
      int q = tid + t*256;
      w3u[2*q]   = pack2bf(rw3[t].x, rw3[t].y);
      w3u[2*q+1] = pack2bf(rw3[t].z, rw3[t].w);
    } }
  if (mode){
    if (tid<73){ float s=0;
      #pragma unroll
      for (int g=0;g<16;g++) s += wsf[WS_PMOM+g*73+tid];
      smom[tid]=s; }
  } else {
    if (tid<73){ float s=0; const float* sm0=wsf+WS_SCRM;
      for (int k=0;k<ACBLK;k++) s += sm0[k*73+tid];
      smom[tid]=s; }
  }
  __syncthreads();
  const float invN = 1.0f/NPTS;
  if (tid < 128){
    int c=tid; float w0=s_w1[3*c],w1=s_w1[3*c+1],w2=s_w1[3*c+2];
    float mean = (w0*smom[0]+w1*smom[1]+w2*smom[2])*invN;
    float ex2 = (w0*w0*smom[3]+w1*w1*smom[6]+w2*w2*smom[8]
               + 2.f*(w0*w1*smom[4]+w0*w2*smom[5]+w1*w2*smom[7]))*invN;
    float var = ex2 - mean*mean;
    float sc = g1[c]*rsqrtf(var+EPS);
    s_sc[c]=sc; s_sh[c]=b1[c]-mean*sc;
  }
  __syncthreads();
  { const unsigned* part=(const unsigned*)wsf+WS_PART;
    const unsigned* mg=(const unsigned*)wsf+WS_MAXG;
    for (int i=tid;i<NB*128;i+=256){
      unsigned u;
      if (mode){ u=0;
        #pragma unroll
        for (int g=0;g<16;g++){ unsigned t=part[g*2048+i]; u = t>u?t:u; }
      } else u = mg[i];
      float M = decodeu(u);               // = max over batch of sign(g1)*y1
      int ch=i&127;
      s_smbn[i] = fabsf(s_sc[ch])*M + s_sh[ch];
    } }
  __syncthreads();
  { int c = tid & 63, which = tid >> 6;
    float s=0;
    for (int j=0;j<128;j++){
      float m = (which<3) ? s_sc[j]*s_w1[3*j+which] : s_sh[j];
      s += w2t[j*66+c]*m;
    }
    if (which<3) sE[which*64+c]=s; else sg[c]=s; }
  for (int i=tid;i<NB*64;i+=256){
    int b=i>>6, c=i&63; float s=0;
    for (int j=0;j<128;j++) s += w2t[(128+j)*66+c]*s_smbn[b*128+j];
    sT[i]=s;
  }
  __syncthreads();
  if (tid < 64){
    int c=tid;
    float e0=sE[c],e1=sE[64+c],e2=sE[128+c],gc=sg[c];
    float sumY = e0*smom[0]+e1*smom[1]+e2*smom[2];
    float sumYY = e0*e0*smom[3]+e1*e1*smom[6]+e2*e2*smom[8]
               + 2.f*(e0*e1*smom[4]+e0*e2*smom[5]+e1*e2*smom[7]);
    #pragma unroll
    for (int b=0;b<NB;b++){
      float nb = smom[9+b*4+3];
      float hb = gc + sT[b*64+c];
      float eS1b = e0*smom[9+b*4]+e1*smom[9+b*4+1]+e2*smom[9+b*4+2];
      sumY += nb*hb;
      sumYY += 2.f*hb*eS1b + nb*hb*hb;
    }
    float mean2 = sumY*invN;
    float var2 = sumYY*invN - mean2*mean2;
    float s2 = g2[c]*rsqrtf(var2+EPS);
    float t2 = b2[c]-mean2*s2;
    s_s2[c]=s2; s_t2[c]=t2;
    wsf[WS_E + c] = e0*s2; wsf[WS_E+64+c]=e1*s2; wsf[WS_E+128+c]=e2*s2;
  }
  __syncthreads();
  for (int i=tid;i<NB*64;i+=256){
    int c=i&63;
    wsf[WS_T + i] = (sg[c]+sT[i])*s_s2[c] + s_t2[c];
  }
}

// ---- kF: fused y2 -> bn2/relu -> z@W3.T + b3 ----
__global__ __launch_bounds__(256) void kF(const float* __restrict__ feats,
                                          const int* __restrict__ bidx,
                                          const float* __restrict__ wsf,
                                          const float* __restrict__ b3,
                                          float* __restrict__ out) {
  __shared__ __align__(16) float Tl[NB*66];
  __shared__ __align__(16) unsigned zbuf[4*64*32];   // 4 waves x 64 rows x 128B
  int tid = threadIdx.x;
  for (int i=tid;i<NB*64;i+=256) Tl[(i>>6)*66 + (i&63)] = wsf[WS_T + i];
  int lane = tid & 63, wv = tid >> 6;
  int col = lane & 15, kgrp = lane >> 4;
  const ushort* w3b = (const ushort*)((const unsigned*)wsf + WS_W3);
  bf16x8 bfr[4][2];
  #pragma unroll
  for (int n=0;n<4;n++)
    #pragma unroll
    for (int kk=0;kk<2;kk++)
      bfr[n][kk] = *(const bf16x8*)(w3b + (n*16+col)*64 + kk*32 + kgrp*8);
  float bias[4];
  #pragma unroll
  for (int n=0;n<4;n++) bias[n] = b3[n*16+col];
  __syncthreads();
  const float* Eg = wsf + WS_E;
  int p0 = (blockIdx.x*4 + wv)*64;
  int p = p0 + lane;
  float f0 = feats[3*p], f1 = feats[3*p+1], f2 = feats[3*p+2];
  int b = bidx[p];
  const float* tb = &Tl[b*66];
  unsigned rowbase = (unsigned)(wv*64+lane)*32;
  unsigned sw = (lane&7)<<2;
  #pragma unroll
  for (int j=0;j<8;j++){
    unsigned w[4];
    #pragma unroll
    for (int q=0;q<4;q++){
      int c = j*8 + q*2;
      float2 tp = *(const float2*)(tb + c);
      float y0 = fmaf(Eg[c],  f0, fmaf(Eg[64+c],  f1, fmaf(Eg[128+c],  f2, tp.x)));
      float y1 = fmaf(Eg[c+1],f0, fmaf(Eg[64+c+1],f1, fmaf(Eg[128+c+1],f2, tp.y)));
      w[q] = pack2bf(fmaxf(y0,0.f), fmaxf(y1,0.f));
    }
    uint4 ch; ch.x=w[0]; ch.y=w[1]; ch.z=w[2]; ch.w=w[3];
    *(uint4*)&zbuf[rowbase + (((unsigned)(j*4)) ^ sw)] = ch;
  }
  __syncthreads();
  bf16x8 af[4][2];
  #pragma unroll
  for (int m=0;m<4;m++){
    int row = m*16 + col;
    unsigned rb = (unsigned)(wv*64+row)*32;
    unsigned sw2 = (unsigned)(row&7)<<2;
    #pragma unroll
    for (int kk=0;kk<2;kk++){
      unsigned off = ((unsigned)(kk*16 + kgrp*4)) ^ sw2;
      af[m][kk] = *(const bf16x8*)&zbuf[rb + off];
    }
  }
  f32x4 acc[4][4];
  #pragma unroll
  for (int m=0;m<4;m++)
    #pragma unroll
    for (int n=0;n<4;n++)
      acc[m][n] = (f32x4){0.f,0.f,0.f,0.f};
  #pragma unroll
  for (int kk=0;kk<2;kk++)
    #pragma unroll
    for (int m=0;m<4;m++)
      #pragma unroll
      for (int n=0;n<4;n++)
        acc[m][n] = __builtin_amdgcn_mfma_f32_16x16x32_bf16(af[m][kk], bfr[n][kk], acc[m][n], 0,0,0);
  #pragma unroll
  for (int m=0;m<4;m++){
    int prow = p0 + m*16 + kgrp*4;
    #pragma unroll
    for (int n=0;n<4;n++){
      int cg = n*16+col;
      #pragma unroll
      for (int r=0;r<4;r++)
        out[(size_t)(prow+r)*64 + cg] = acc[m][n][r] + bias[n];
    }
  }
}

extern "C" void kernel_launch(void* const* d_in, const int* in_sizes, int n_in,
                              void* d_out, int out_size, void* d_ws, size_t ws_size,
                              hipStream_t stream) {
  const float* feats = (const float*)d_in[0];
  const int*   bidx  = (const int*)d_in[1];
  const float* W1 = (const float*)d_in[2];
  const float* g1 = (const float*)d_in[3];
  const float* b1 = (const float*)d_in[4];
  const float* W2 = (const float*)d_in[5];
  const float* g2 = (const float*)d_in[6];
  const float* b2 = (const float*)d_in[7];
  const float* W3 = (const float*)d_in[8];
  const float* b3 = (const float*)d_in[9];
  float* wsf = (float*)d_ws;
  float* out = (float*)d_out;
  size_t need = (size_t)(WS_SMAX + (size_t)ACBLK*2048)*4;
  int mode = (ws_size >= need) ? 1 : 0;
  if (!mode) (void)hipMemsetAsync((char*)d_ws + (size_t)WS_MAXG*4, 0, 2048*4, stream);
  kAC<<<ACBLK, 256, 0, stream>>>(feats, bidx, W1, g1, wsf, mode);
  if (mode) kM<<<128, 256, 0, stream>>>(wsf);
  kB<<<1, 256, 0, stream>>>(wsf, W1,g1,b1, W2,g2,b2, W3, mode);
  kF<<<1024, 256, 0, stream>>>(feats, bidx, wsf, b3, out);
}

// Round 7
// 62.104 us; speedup vs baseline: 1.3138x; 1.2856x over previous
//
#include <hip/hip_runtime.h>
#include <hip/hip_bf16.h>

#define EPS 1e-5f
#define NPTS 262144
#define NB 16
#define ACBLK 1024

typedef __attribute__((ext_vector_type(8))) short bf16x8;
typedef __attribute__((ext_vector_type(4))) float f32x4;

// ws float/u32 offsets
#define WS_E    0        // 192 f
#define WS_T    192      // 1024 f
#define WS_W3   1216     // 2048 u32
#define WS_MAXG 3264     // 2048 u32 fallback merged maxima (memset 0 in mode 0)
#define WS_PMOM 5312     // 16*73 f kM partial moments
#define WS_SCRM 6480     // 1024*73 f per-block moments(9)+hist(64)
#define WS_PART 81232    // 16*2048 u32 kM partial maxima
#define WS_SMAX 114000   // 1024*2048 u32 per-block maxima

__device__ inline float decodeu(unsigned u){
  unsigned bits = (u & 0x80000000u) ? (u ^ 0x80000000u) : ~u;
  return __uint_as_float(bits);
}
__device__ inline unsigned f2bf(float f){
  unsigned u = __float_as_uint(f);
  return (u + 0x7FFFu + ((u>>16)&1u)) >> 16;
}
__device__ inline unsigned pack2bf(float lo, float hi){
  return (f2bf(hi)<<16) | (f2bf(lo) & 0xFFFFu);
}
__device__ inline unsigned ordu(float v){
  unsigned bits = __float_as_uint(v);
  return bits ^ (unsigned)(((int)bits>>31) | (int)0x80000000);
}

// ---- kAC: fused moments + per-batch directional max of feats@W1'^T ----
__global__ __launch_bounds__(256) void kAC(const float* __restrict__ feats,
                                           const int* __restrict__ bidx,
                                           const float* __restrict__ W1,
                                           const float* __restrict__ g1,
                                           float* __restrict__ wsf, int mode) {
  __shared__ unsigned lmax[NB*128];          // 8KB
  __shared__ __align__(16) float4 sfeat[256];// 4KB
  __shared__ float hist[NB*4];
  __shared__ float red[4*9];
  int tid = threadIdx.x;
  for (int i=tid;i<NB*128;i+=256) lmax[i]=0u;
  if (tid < NB*4) hist[tid]=0.f;
  __syncthreads();
  int p = blockIdx.x*256 + tid;
  float f0=feats[3*p], f1=feats[3*p+1], f2=feats[3*p+2];
  int b = bidx[p];
  sfeat[tid] = make_float4(f0,f1,f2,__int_as_float(b));
  atomicAdd(&hist[b*4+0],f0);
  atomicAdd(&hist[b*4+1],f1);
  atomicAdd(&hist[b*4+2],f2);
  atomicAdd(&hist[b*4+3],1.0f);
  int lane = tid&63, wv = tid>>6;
  { float acc[9]={f0,f1,f2,f0*f0,f0*f1,f0*f2,f1*f1,f1*f2,f2*f2};
    #pragma unroll
    for (int k=0;k<9;k++){
      float v=acc[k];
      v+=__shfl_down(v,32); v+=__shfl_down(v,16); v+=__shfl_down(v,8);
      v+=__shfl_down(v,4);  v+=__shfl_down(v,2);  v+=__shfl_down(v,1);
      if (lane==0) red[wv*9+k]=v;
    }
  }
  __syncthreads();
  int c = (wv&1)*64 + lane;
  float sgn = (g1[c]>=0.f)?1.f:-1.f;
  float w0=W1[3*c]*sgn, w1=W1[3*c+1]*sgn, w2=W1[3*c+2]*sgn;
  const float4* sp = &sfeat[(wv>>1)*128];
  float m[16];
  #pragma unroll
  for (int q=0;q<16;q++) m[q] = -__builtin_inff();
  #pragma unroll 8
  for (int k=0;k<128;k++){
    float4 f = sp[k];
    float v = fmaf(f.z,w2,fmaf(f.y,w1,f.x*w0));
    int sbb = __builtin_amdgcn_readfirstlane(__float_as_int(f.w));
    switch (sbb){
      case 0:  m[0] = fmaxf(m[0], v); break;
      case 1:  m[1] = fmaxf(m[1], v); break;
      case 2:  m[2] = fmaxf(m[2], v); break;
      case 3:  m[3] = fmaxf(m[3], v); break;
      case 4:  m[4] = fmaxf(m[4], v); break;
      case 5:  m[5] = fmaxf(m[5], v); break;
      case 6:  m[6] = fmaxf(m[6], v); break;
      case 7:  m[7] = fmaxf(m[7], v); break;
      case 8:  m[8] = fmaxf(m[8], v); break;
      case 9:  m[9] = fmaxf(m[9], v); break;
      case 10: m[10] = fmaxf(m[10], v); break;
      case 11: m[11] = fmaxf(m[11], v); break;
      case 12: m[12] = fmaxf(m[12], v); break;
      case 13: m[13] = fmaxf(m[13], v); break;
      case 14: m[14] = fmaxf(m[14], v); break;
      default: m[15] = fmaxf(m[15], v); break;
    }
  }
  #pragma unroll
  for (int q=0;q<16;q++){
    if (m[q] > -__builtin_inff()) atomicMax(&lmax[q*128+c], ordu(m[q]));
  }
  __syncthreads();
  float* scrM = wsf + WS_SCRM + blockIdx.x*73;
  if (tid<9) scrM[tid]=red[tid]+red[9+tid]+red[18+tid]+red[27+tid];
  if (tid>=64 && tid<128) scrM[9+tid-64]=hist[tid-64];
  if (mode){
    unsigned* spo = (unsigned*)wsf + WS_SMAX + (size_t)blockIdx.x*2048;
    for (int i=tid;i<2048;i+=256) spo[i]=lmax[i];
  } else {
    unsigned* mg = (unsigned*)wsf + WS_MAXG;
    for (int i=tid;i<2048;i+=256){ unsigned v=lmax[i]; if(v) atomicMax(&mg[i],v); }
  }
}

// ---- kM: tree-merge per-block maxima 1024->16, moments 1024->16 ----
__global__ __launch_bounds__(256) void kM(float* __restrict__ wsf){
  int g = blockIdx.x >> 3, ec = blockIdx.x & 7;
  int e = ec*256 + threadIdx.x;
  const unsigned* smax = (const unsigned*)wsf + WS_SMAX;
  unsigned m = 0;
  #pragma unroll 4
  for (int k=g*64;k<g*64+64;k++){ unsigned t=smax[(size_t)k*2048+e]; m = t>m?t:m; }
  ((unsigned*)wsf)[WS_PART + g*2048 + e] = m;
  if (ec==0 && threadIdx.x<73){
    float s=0; const float* sm0 = wsf + WS_SCRM;
    #pragma unroll 4
    for (int k=g*64;k<g*64+64;k++) s += sm0[k*73+threadIdx.x];
    wsf[WS_PMOM + g*73 + threadIdx.x] = s;
  }
}

// ---- kB: all tiny math (single block, 1024 thr, float4 LDS dots) ----
__global__ __launch_bounds__(1024) void kB(float* __restrict__ wsf,
    const float* __restrict__ W1, const float* __restrict__ g1, const float* __restrict__ b1,
    const float* __restrict__ W2, const float* __restrict__ g2, const float* __restrict__ b2,
    const float* __restrict__ W3, int mode) {
  __shared__ __align__(16) float4 w2q[64*66];   // [jj4][c] j-quads, pad 66
  __shared__ __align__(16) float4 smbnq[NB*32]; // [b][jj] rhs for sT (W2 cols 128+)
  __shared__ __align__(16) float4 srhsq[4*32];  // E0,E1,E2,sh rhs (W2 cols 0-127)
  __shared__ float s_w1[384];
  __shared__ float s_sc[128], s_sh[128], sE[3*64], sg[64], sT[NB*64];
  __shared__ float smom[80], s_s2[64], s_t2[64];
  int tid = threadIdx.x;
  // stage: 4 float4 W2 loads + 1 float4 W3 + W1 + smom (all independent)
  float4 rw[4];
  #pragma unroll
  for (int t=0;t<4;t++) rw[t] = ((const float4*)W2)[tid + t*1024];
  float4 rw3 = ((const float4*)W3)[tid];
  if (tid<384) s_w1[tid]=W1[tid];
  #pragma unroll
  for (int t=0;t<4;t++){
    int q = tid + t*1024;
    w2q[(q&63)*66 + (q>>6)] = rw[t];
  }
  { unsigned* w3u = (unsigned*)wsf + WS_W3;
    w3u[2*tid]   = pack2bf(rw3.x, rw3.y);
    w3u[2*tid+1] = pack2bf(rw3.z, rw3.w);
  }
  if (mode){
    if (tid<73){ float s=0;
      #pragma unroll
      for (int g=0;g<16;g++) s += wsf[WS_PMOM+g*73+tid];
      smom[tid]=s; }
  } else {
    if (tid<73){ float s=0; const float* sm0=wsf+WS_SCRM;
      for (int k=0;k<ACBLK;k++) s += sm0[k*73+tid];
      smom[tid]=s; }
  }
  __syncthreads();
  const float invN = 1.0f/NPTS;
  if (tid < 128){
    int c=tid; float w0=s_w1[3*c],w1=s_w1[3*c+1],w2=s_w1[3*c+2];
    float mean = (w0*smom[0]+w1*smom[1]+w2*smom[2])*invN;
    float ex2 = (w0*w0*smom[3]+w1*w1*smom[6]+w2*w2*smom[8]
               + 2.f*(w0*w1*smom[4]+w0*w2*smom[5]+w1*w2*smom[7]))*invN;
    float var = ex2 - mean*mean;
    float sc = g1[c]*rsqrtf(var+EPS);
    s_sc[c]=sc; s_sh[c]=b1[c]-mean*sc;
  }
  __syncthreads();
  // build rhs arrays
  { const unsigned* part=(const unsigned*)wsf+WS_PART;
    const unsigned* mg=(const unsigned*)wsf+WS_MAXG;
    float* smbnf = (float*)smbnq;
    #pragma unroll
    for (int i=tid;i<NB*128;i+=1024){
      unsigned u;
      if (mode){ u=0;
        #pragma unroll
        for (int g=0;g<16;g++){ unsigned t=part[g*2048+i]; u = t>u?t:u; }
      } else u = mg[i];
      float M = decodeu(u);
      int ch=i&127;
      smbnf[i] = fabsf(s_sc[ch])*M + s_sh[ch];
    } }
  if (tid < 512){
    int which = tid>>7, j = tid&127;
    ((float*)srhsq)[tid] = (which<3) ? s_sc[j]*s_w1[3*j+which] : s_sh[j];
  }
  __syncthreads();
  // dot pass: 1024 sT dots + 256 sE/sg dots
  { int c = tid&63, b = tid>>6;
    const float4* rq = &smbnq[b*32];
    float s=0;
    #pragma unroll 8
    for (int jj=0;jj<32;jj++){
      float4 a = w2q[(32+jj)*66 + c];
      float4 r = rq[jj];
      s = fmaf(a.x,r.x,fmaf(a.y,r.y,fmaf(a.z,r.z,fmaf(a.w,r.w,s))));
    }
    sT[b*64+c] = s;
    if (tid < 256){
      int which = tid>>6;
      float s2=0;
      #pragma unroll 8
      for (int jj=0;jj<32;jj++){
        float4 a = w2q[jj*66 + c];
        float4 r = srhsq[which*32+jj];
        s2 = fmaf(a.x,r.x,fmaf(a.y,r.y,fmaf(a.z,r.z,fmaf(a.w,r.w,s2))));
      }
      if (which<3) sE[which*64+c]=s2; else sg[c]=s2;
    }
  }
  __syncthreads();
  if (tid < 64){
    int c=tid;
    float e0=sE[c],e1=sE[64+c],e2=sE[128+c],gc=sg[c];
    float sumY = e0*smom[0]+e1*smom[1]+e2*smom[2];
    float sumYY = e0*e0*smom[3]+e1*e1*smom[6]+e2*e2*smom[8]
               + 2.f*(e0*e1*smom[4]+e0*e2*smom[5]+e1*e2*smom[7]);
    #pragma unroll
    for (int b=0;b<NB;b++){
      float nb = smom[9+b*4+3];
      float hb = gc + sT[b*64+c];
      float eS1b = e0*smom[9+b*4]+e1*smom[9+b*4+1]+e2*smom[9+b*4+2];
      sumY += nb*hb;
      sumYY += 2.f*hb*eS1b + nb*hb*hb;
    }
    float mean2 = sumY*invN;
    float var2 = sumYY*invN - mean2*mean2;
    float s2 = g2[c]*rsqrtf(var2+EPS);
    float t2 = b2[c]-mean2*s2;
    s_s2[c]=s2; s_t2[c]=t2;
    wsf[WS_E + c] = e0*s2; wsf[WS_E+64+c]=e1*s2; wsf[WS_E+128+c]=e2*s2;
  }
  __syncthreads();
  { int c=tid&63;
    if (tid < NB*64) wsf[WS_T + tid] = (sg[c]+sT[tid])*s_s2[c] + s_t2[c];
  }
}

// ---- kF: fused y2 -> bn2/relu -> z@W3.T + b3 ----
__global__ __launch_bounds__(256) void kF(const float* __restrict__ feats,
                                          const int* __restrict__ bidx,
                                          const float* __restrict__ wsf,
                                          const float* __restrict__ b3,
                                          float* __restrict__ out) {
  __shared__ __align__(16) float Tl[NB*66];
  __shared__ __align__(16) unsigned zbuf[4*64*32];   // 4 waves x 64 rows x 128B
  int tid = threadIdx.x;
  for (int i=tid;i<NB*64;i+=256) Tl[(i>>6)*66 + (i&63)] = wsf[WS_T + i];
  int lane = tid & 63, wv = tid >> 6;
  int col = lane & 15, kgrp = lane >> 4;
  const ushort* w3b = (const ushort*)((const unsigned*)wsf + WS_W3);
  bf16x8 bfr[4][2];
  #pragma unroll
  for (int n=0;n<4;n++)
    #pragma unroll
    for (int kk=0;kk<2;kk++)
      bfr[n][kk] = *(const bf16x8*)(w3b + (n*16+col)*64 + kk*32 + kgrp*8);
  float bias[4];
  #pragma unroll
  for (int n=0;n<4;n++) bias[n] = b3[n*16+col];
  __syncthreads();
  const float* Eg = wsf + WS_E;
  int p0 = (blockIdx.x*4 + wv)*64;
  int p = p0 + lane;
  float f0 = feats[3*p], f1 = feats[3*p+1], f2 = feats[3*p+2];
  int b = bidx[p];
  const float* tb = &Tl[b*66];
  unsigned rowbase = (unsigned)(wv*64+lane)*32;
  unsigned sw = (lane&7)<<2;
  #pragma unroll
  for (int j=0;j<8;j++){
    unsigned w[4];
    #pragma unroll
    for (int q=0;q<4;q++){
      int c = j*8 + q*2;
      float2 tp = *(const float2*)(tb + c);
      float y0 = fmaf(Eg[c],  f0, fmaf(Eg[64+c],  f1, fmaf(Eg[128+c],  f2, tp.x)));
      float y1 = fmaf(Eg[c+1],f0, fmaf(Eg[64+c+1],f1, fmaf(Eg[128+c+1],f2, tp.y)));
      w[q] = pack2bf(fmaxf(y0,0.f), fmaxf(y1,0.f));
    }
    uint4 ch; ch.x=w[0]; ch.y=w[1]; ch.z=w[2]; ch.w=w[3];
    *(uint4*)&zbuf[rowbase + (((unsigned)(j*4)) ^ sw)] = ch;
  }
  __syncthreads();
  bf16x8 af[4][2];
  #pragma unroll
  for (int m=0;m<4;m++){
    int row = m*16 + col;
    unsigned rb = (unsigned)(wv*64+row)*32;
    unsigned sw2 = (unsigned)(row&7)<<2;
    #pragma unroll
    for (int kk=0;kk<2;kk++){
      unsigned off = ((unsigned)(kk*16 + kgrp*4)) ^ sw2;
      af[m][kk] = *(const bf16x8*)&zbuf[rb + off];
    }
  }
  f32x4 acc[4][4];
  #pragma unroll
  for (int m=0;m<4;m++)
    #pragma unroll
    for (int n=0;n<4;n++)
      acc[m][n] = (f32x4){0.f,0.f,0.f,0.f};
  #pragma unroll
  for (int kk=0;kk<2;kk++)
    #pragma unroll
    for (int m=0;m<4;m++)
      #pragma unroll
      for (int n=0;n<4;n++)
        acc[m][n] = __builtin_amdgcn_mfma_f32_16x16x32_bf16(af[m][kk], bfr[n][kk], acc[m][n], 0,0,0);
  #pragma unroll
  for (int m=0;m<4;m++){
    int prow = p0 + m*16 + kgrp*4;
    #pragma unroll
    for (int n=0;n<4;n++){
      int cg = n*16+col;
      #pragma unroll
      for (int r=0;r<4;r++)
        out[(size_t)(prow+r)*64 + cg] = acc[m][n][r] + bias[n];
    }
  }
}

extern "C" void kernel_launch(void* const* d_in, const int* in_sizes, int n_in,
                              void* d_out, int out_size, void* d_ws, size_t ws_size,
                              hipStream_t stream) {
  const float* feats = (const float*)d_in[0];
  const int*   bidx  = (const int*)d_in[1];
  const float* W1 = (const float*)d_in[2];
  const float* g1 = (const float*)d_in[3];
  const float* b1 = (const float*)d_in[4];
  const float* W2 = (const float*)d_in[5];
  const float* g2 = (const float*)d_in[6];
  const float* b2 = (const float*)d_in[7];
  const float* W3 = (const float*)d_in[8];
  const float* b3 = (const float*)d_in[9];
  float* wsf = (float*)d_ws;
  float* out = (float*)d_out;
  size_t need = (size_t)(WS_SMAX + (size_t)ACBLK*2048)*4;
  int mode = (ws_size >= need) ? 1 : 0;
  if (!mode) (void)hipMemsetAsync((char*)d_ws + (size_t)WS_MAXG*4, 0, 2048*4, stream);
  kAC<<<ACBLK, 256, 0, stream>>>(feats, bidx, W1, g1, wsf, mode);
  if (mode) kM<<<128, 256, 0, stream>>>(wsf);
  kB<<<1, 1024, 0, stream>>>(wsf, W1,g1,b1, W2,g2,b2, W3, mode);
  kF<<<1024, 256, 0, stream>>>(feats, bidx, wsf, b3, out);
}